// Round 1
// baseline (304.898 us; speedup 1.0000x reference)
//
#include <hip/hip_runtime.h>
#include <hip/hip_bf16.h>
#include <stdint.h>

#define D_MODEL 1024
#define NH 16
#define DH 64
#define SEQ 2048
#define NBATCH 2
#define MROWS 4096   // B*S

typedef unsigned short ushort_t;
typedef __attribute__((ext_vector_type(4))) float f32x4;
typedef __attribute__((ext_vector_type(4))) unsigned short us4;
typedef __attribute__((ext_vector_type(8))) unsigned short us8;
typedef __attribute__((ext_vector_type(8))) __bf16 bf16x8;

__device__ __forceinline__ f32x4 mfma16x16x32(us8 a, us8 b, f32x4 c) {
    return __builtin_amdgcn_mfma_f32_16x16x32_bf16(
        __builtin_bit_cast(bf16x8, a), __builtin_bit_cast(bf16x8, b), c, 0, 0, 0);
}

// fp32 -> bf16 round-to-nearest-even (finite inputs)
__device__ __forceinline__ ushort_t f2bf(float f) {
    union { float f; uint32_t u; } v; v.f = f;
    uint32_t r = v.u + 0x7fffu + ((v.u >> 16) & 1u);
    return (ushort_t)(r >> 16);
}

__device__ __forceinline__ us8 cat44(us4 lo, us4 hi) {
    us8 r;
    r[0] = lo[0]; r[1] = lo[1]; r[2] = lo[2]; r[3] = lo[3];
    r[4] = hi[0]; r[5] = hi[1]; r[6] = hi[2]; r[7] = hi[3];
    return r;
}

// ---------------------------------------------------------------------------
// GEMM  C = A @ W^T   (A: [4096][1024], W: [1024][1024] row-major [out][in])
// MODE 0: A fp32; epilogue: scatter bf16 to [B,H,S,Dh] with scale (Q/K/V proj)
// MODE 1: A bf16 (row-major); epilogue: fp32 flat [4096][1024] (final proj)
// ---------------------------------------------------------------------------
#define BM 128
#define BN 128
#define BK 32
#define PADK 40   // LDS row stride in bf16 elems (80 B: 16B-aligned, conflict-free b64 frag reads)

template<int MODE>
__global__ __launch_bounds__(256) void gemm_bt(const void* __restrict__ Ap,
                                               const float* __restrict__ W,
                                               void* __restrict__ Cp,
                                               float scale)
{
    __shared__ ushort_t sA[BM * PADK];
    __shared__ ushort_t sB[BN * PADK];
    const int t = threadIdx.x;
    const int lane = t & 63;
    const int w = t >> 6;
    const int wm = (w >> 1) * 64, wn = (w & 1) * 64;
    const int m0 = blockIdx.x * BM, n0 = blockIdx.y * BN;
    const int lr = lane & 15, lg = lane >> 4;

    f32x4 acc[4][4];
    f32x4 zero = {0.f, 0.f, 0.f, 0.f};
#pragma unroll
    for (int i = 0; i < 4; i++)
#pragma unroll
        for (int j = 0; j < 4; j++) acc[i][j] = zero;

    for (int k0 = 0; k0 < D_MODEL; k0 += BK) {
        __syncthreads();
        // ---- stage A tile [128][32] ----
        if (MODE == 0) {
            const float* A = (const float*)Ap;
#pragma unroll
            for (int i = 0; i < 4; i++) {
                int idx = t + i * 256;              // float4 idx: 128 rows x 8
                int row = idx >> 3, c4 = (idx & 7) * 4;
                float4 v = *(const float4*)(A + (size_t)(m0 + row) * D_MODEL + k0 + c4);
                us4 s;
                s[0] = f2bf(v.x); s[1] = f2bf(v.y); s[2] = f2bf(v.z); s[3] = f2bf(v.w);
                *(us4*)&sA[row * PADK + c4] = s;
            }
        } else {
            const ushort_t* A = (const ushort_t*)Ap;
#pragma unroll
            for (int i = 0; i < 2; i++) {
                int idx = t + i * 256;              // 8-elem chunk: 128 rows x 4
                int row = idx >> 2, c8 = (idx & 3) * 8;
                us8 v = *(const us8*)(A + (size_t)(m0 + row) * D_MODEL + k0 + c8);
                *(us8*)&sA[row * PADK + c8] = v;    // byte: row*80 + c8*2 -> 16B aligned
            }
        }
        // ---- stage B tile (W fp32) [128][32] ----
#pragma unroll
        for (int i = 0; i < 4; i++) {
            int idx = t + i * 256;
            int row = idx >> 3, c4 = (idx & 7) * 4;
            float4 v = *(const float4*)(W + (size_t)(n0 + row) * D_MODEL + k0 + c4);
            us4 s;
            s[0] = f2bf(v.x); s[1] = f2bf(v.y); s[2] = f2bf(v.z); s[3] = f2bf(v.w);
            *(us4*)&sB[row * PADK + c4] = s;
        }
        __syncthreads();

        // ---- fragments + 16 MFMA ----
        us8 af[4], bfr[4];
#pragma unroll
        for (int f = 0; f < 4; f++) {
            const ushort_t* pa = &sA[(wm + f * 16 + lr) * PADK + 4 * lg];
            af[f] = cat44(*(const us4*)pa, *(const us4*)(pa + 16));
            const ushort_t* pb = &sB[(wn + f * 16 + lr) * PADK + 4 * lg];
            bfr[f] = cat44(*(const us4*)pb, *(const us4*)(pb + 16));
        }
#pragma unroll
        for (int i = 0; i < 4; i++)
#pragma unroll
            for (int j = 0; j < 4; j++)
                acc[i][j] = mfma16x16x32(af[i], bfr[j], acc[i][j]);
    }

    // ---- epilogue ----
    if (MODE == 0) {
        ushort_t* C = (ushort_t*)Cp;
#pragma unroll
        for (int i = 0; i < 4; i++)
#pragma unroll
            for (int j = 0; j < 4; j++)
#pragma unroll
                for (int r = 0; r < 4; r++) {
                    int m = m0 + wm + i * 16 + 4 * lg + r;   // token row (b*S+s)
                    int n = n0 + wn + j * 16 + lr;           // feature col
                    int b = m >> 11, s = m & 2047;
                    int h = n >> 6, dh = n & 63;
                    C[(((size_t)(b * NH + h)) * SEQ + s) * DH + dh] = f2bf(acc[i][j][r] * scale);
                }
    } else {
        float* C = (float*)Cp;
#pragma unroll
        for (int i = 0; i < 4; i++)
#pragma unroll
            for (int j = 0; j < 4; j++)
#pragma unroll
                for (int r = 0; r < 4; r++) {
                    int m = m0 + wm + i * 16 + 4 * lg + r;
                    int n = n0 + wn + j * 16 + lr;
                    C[(size_t)m * D_MODEL + n] = acc[i][j][r];
                }
    }
}

// ---------------------------------------------------------------------------
// mask tile flags: flag[qt][kt] = any nonzero in mask[qt*128..+128)[kt*64..+64)
// ---------------------------------------------------------------------------
__global__ __launch_bounds__(256) void mask_flags(const float* __restrict__ mask,
                                                  int* __restrict__ flags)
{
    int qt = blockIdx.x, kt = blockIdx.y;
    int t = threadIdx.x;
    bool nz = false;
#pragma unroll
    for (int i = 0; i < 8; i++) {
        int idx = t + i * 256;               // 2048 float4: 128 rows x 16
        int row = idx >> 4, c4 = (idx & 15) * 4;
        float4 v = *(const float4*)(mask + (size_t)(qt * 128 + row) * SEQ + kt * 64 + c4);
        nz |= (v.x != 0.f) | (v.y != 0.f) | (v.z != 0.f) | (v.w != 0.f);
    }
    if (__any((int)nz) && (t & 63) == 0) atomicOr(&flags[qt * 32 + kt], 1);
}

// ---------------------------------------------------------------------------
// Flash attention: block = (q-tile of 128, head). 4 waves x 32 q-rows.
// Q pre-scaled by 1/sqrt(Dh). K,V: [B*H][S][Dh] bf16. Out: [B*S][D] bf16.
// ---------------------------------------------------------------------------
#define KPAD 68
#define PPAD 68

__global__ __launch_bounds__(256) void attn_fwd(const ushort_t* __restrict__ Q,
                                                const ushort_t* __restrict__ K,
                                                const ushort_t* __restrict__ V,
                                                const float* __restrict__ mask,
                                                const int* __restrict__ flags,
                                                ushort_t* __restrict__ O)
{
    __shared__ ushort_t sK[64 * KPAD];
    __shared__ ushort_t sVT[64 * KPAD];
    __shared__ ushort_t sP[4][32 * PPAD];

    const int t = threadIdx.x, lane = t & 63, w = t >> 6;
    const int lr = lane & 15, lg = lane >> 4;
    const int qt = blockIdx.x, bh = blockIdx.y;
    const int b = bh >> 4, h = bh & 15;
    const int q0 = qt * 128 + w * 32;        // wave's first q row in S

    // preload Q fragments: [fm][kstep]
    us8 qf[2][2];
#pragma unroll
    for (int fm = 0; fm < 2; fm++)
#pragma unroll
        for (int ks = 0; ks < 2; ks++) {
            const ushort_t* p = Q + ((size_t)bh * SEQ + q0 + fm * 16 + lr) * DH + ks * 32 + 4 * lg;
            qf[fm][ks] = cat44(*(const us4*)p, *(const us4*)(p + 16));
        }

    f32x4 zero = {0.f, 0.f, 0.f, 0.f};
    f32x4 acc_o[2][4];
#pragma unroll
    for (int i = 0; i < 2; i++)
#pragma unroll
        for (int j = 0; j < 4; j++) acc_o[i][j] = zero;
    float m_run[2][4], l_run[2][4];
#pragma unroll
    for (int i = 0; i < 2; i++)
#pragma unroll
        for (int r = 0; r < 4; r++) { m_run[i][r] = -1e30f; l_run[i][r] = 0.f; }

    const ushort_t* Kb = K + (size_t)bh * SEQ * DH;
    const ushort_t* Vb = V + (size_t)bh * SEQ * DH;

    for (int kvt = 0; kvt < SEQ / 64; ++kvt) {
        __syncthreads();
        // ---- stage K [64][64] ----
#pragma unroll
        for (int i = 0; i < 4; i++) {
            int idx = t + i * 256;            // 1024 chunks of 4 elems: 64 rows x 16
            int row = idx >> 4, c = (idx & 15) * 4;
            us4 v = *(const us4*)(Kb + (size_t)(kvt * 64 + row) * DH + c);
            *(us4*)&sK[row * KPAD + c] = v;
        }
        // ---- stage V transposed: sVT[d][kv] ----
        {
            int kv = t >> 2, c0 = (t & 3) * 16;
            const ushort_t* p = Vb + (size_t)(kvt * 64 + kv) * DH + c0;
            us8 v0 = *(const us8*)p;
            us8 v1 = *(const us8*)(p + 8);
#pragma unroll
            for (int i = 0; i < 8; i++) sVT[(c0 + i) * KPAD + kv] = v0[i];
#pragma unroll
            for (int i = 0; i < 8; i++) sVT[(c0 + 8 + i) * KPAD + kv] = v1[i];
        }
        __syncthreads();

        // ---- scores = Q K^T (pre-scaled) ----
        f32x4 s_acc[2][4];
#pragma unroll
        for (int i = 0; i < 2; i++)
#pragma unroll
            for (int j = 0; j < 4; j++) s_acc[i][j] = zero;
        us8 kf[4][2];
#pragma unroll
        for (int fn = 0; fn < 4; fn++)
#pragma unroll
            for (int ks = 0; ks < 2; ks++) {
                const ushort_t* p = &sK[(fn * 16 + lr) * KPAD + ks * 32 + 4 * lg];
                kf[fn][ks] = cat44(*(const us4*)p, *(const us4*)(p + 16));
            }
#pragma unroll
        for (int fm = 0; fm < 2; fm++)
#pragma unroll
            for (int fn = 0; fn < 4; fn++)
#pragma unroll
                for (int ks = 0; ks < 2; ks++)
                    s_acc[fm][fn] = mfma16x16x32(qf[fm][ks], kf[fn][ks], s_acc[fm][fn]);

        // ---- additive mask (skipped when tile is all-zero) ----
        if (flags[qt * 32 + kvt]) {
#pragma unroll
            for (int fm = 0; fm < 2; fm++)
#pragma unroll
                for (int r = 0; r < 4; r++) {
                    int q = q0 + fm * 16 + 4 * lg + r;
#pragma unroll
                    for (int fn = 0; fn < 4; fn++)
                        s_acc[fm][fn][r] += mask[(size_t)q * SEQ + kvt * 64 + fn * 16 + lr];
                }
        }

        // ---- online softmax ----
#pragma unroll
        for (int fm = 0; fm < 2; fm++)
#pragma unroll
            for (int r = 0; r < 4; r++) {
                float mx = fmaxf(fmaxf(s_acc[fm][0][r], s_acc[fm][1][r]),
                                 fmaxf(s_acc[fm][2][r], s_acc[fm][3][r]));
#pragma unroll
                for (int off = 1; off < 16; off <<= 1) mx = fmaxf(mx, __shfl_xor(mx, off));
                float mnew = fmaxf(m_run[fm][r], mx);
                float sc = __expf(m_run[fm][r] - mnew);
                m_run[fm][r] = mnew;
                float rs = 0.f;
#pragma unroll
                for (int fn = 0; fn < 4; fn++) {
                    float p = __expf(s_acc[fm][fn][r] - mnew);
                    s_acc[fm][fn][r] = p;
                    rs += p;
                }
#pragma unroll
                for (int off = 1; off < 16; off <<= 1) rs += __shfl_xor(rs, off);
                l_run[fm][r] = l_run[fm][r] * sc + rs;
#pragma unroll
                for (int fd = 0; fd < 4; fd++) acc_o[fm][fd][r] *= sc;
#pragma unroll
                for (int fn = 0; fn < 4; fn++)
                    sP[w][(fm * 16 + 4 * lg + r) * PPAD + fn * 16 + lr] = f2bf(s_acc[fm][fn][r]);
            }

        // ---- O += P @ V ----
        us8 vf[4][2];
#pragma unroll
        for (int fd = 0; fd < 4; fd++)
#pragma unroll
            for (int ks = 0; ks < 2; ks++) {
                const ushort_t* p = &sVT[(fd * 16 + lr) * KPAD + ks * 32 + 4 * lg];
                vf[fd][ks] = cat44(*(const us4*)p, *(const us4*)(p + 16));
            }
#pragma unroll
        for (int fm = 0; fm < 2; fm++)
#pragma unroll
            for (int ks = 0; ks < 2; ks++) {
                const ushort_t* p = &sP[w][(fm * 16 + lr) * PPAD + ks * 32 + 4 * lg];
                us8 pf = cat44(*(const us4*)p, *(const us4*)(p + 16));
#pragma unroll
                for (int fd = 0; fd < 4; fd++)
                    acc_o[fm][fd] = mfma16x16x32(pf, vf[fd][ks], acc_o[fm][fd]);
            }
    }

    // ---- normalize + write [B*S][D] bf16 ----
#pragma unroll
    for (int fm = 0; fm < 2; fm++)
#pragma unroll
        for (int r = 0; r < 4; r++) {
            float inv = 1.f / l_run[fm][r];
            int q = q0 + fm * 16 + 4 * lg + r;
#pragma unroll
            for (int fd = 0; fd < 4; fd++) {
                int d = fd * 16 + lr;
                O[((size_t)(b * SEQ + q)) * D_MODEL + h * DH + d] = f2bf(acc_o[fm][fd][r] * inv);
            }
        }
}

// ---------------------------------------------------------------------------
extern "C" void kernel_launch(void* const* d_in, const int* in_sizes, int n_in,
                              void* d_out, int out_size, void* d_ws, size_t ws_size,
                              hipStream_t stream)
{
    const float* qx   = (const float*)d_in[0];
    const float* kx   = (const float*)d_in[1];
    const float* vx   = (const float*)d_in[2];
    const float* mask = (const float*)d_in[3];
    const float* wq   = (const float*)d_in[4];
    const float* wk   = (const float*)d_in[5];
    const float* wv   = (const float*)d_in[6];
    const float* w0   = (const float*)d_in[7];
    float* out = (float*)d_out;

    char* ws = (char*)d_ws;
    const size_t MB = 1024 * 1024;
    ushort_t* Q  = (ushort_t*)(ws);                 // [B,H,S,Dh] bf16, 8 MB
    ushort_t* K  = (ushort_t*)(ws + 8 * MB);
    ushort_t* V  = (ushort_t*)(ws + 16 * MB);
    ushort_t* AO = (ushort_t*)(ws + 24 * MB);       // [B*S][D] bf16, 8 MB
    int* flags   = (int*)(ws + 32 * MB);            // [16][32]

    hipMemsetAsync(flags, 0, 16 * 32 * sizeof(int), stream);
    mask_flags<<<dim3(16, 32), 256, 0, stream>>>(mask, flags);

    dim3 g(MROWS / BM, D_MODEL / BN);               // (32, 8)
    gemm_bt<0><<<g, 256, 0, stream>>>(qx, wq, Q, 0.125f);  // fold 1/sqrt(64) into Q
    gemm_bt<0><<<g, 256, 0, stream>>>(kx, wk, K, 1.0f);
    gemm_bt<0><<<g, 256, 0, stream>>>(vx, wv, V, 1.0f);

    attn_fwd<<<dim3(16, 32), 256, 0, stream>>>(Q, K, V, mask, flags, AO);

    gemm_bt<1><<<g, 256, 0, stream>>>(AO, w0, out, 1.0f);
}

// Round 2
// 244.839 us; speedup vs baseline: 1.2453x; 1.2453x over previous
//
#include <hip/hip_runtime.h>
#include <hip/hip_bf16.h>
#include <stdint.h>

#define D_MODEL 1024
#define NH 16
#define DH 64
#define SEQ 2048
#define MROWS 4096   // B*S

typedef unsigned short ushort_t;
typedef __attribute__((ext_vector_type(4))) float f32x4;
typedef __attribute__((ext_vector_type(4))) unsigned short us4;
typedef __attribute__((ext_vector_type(8))) unsigned short us8;
typedef __attribute__((ext_vector_type(8))) __bf16 bf16x8;

__device__ __forceinline__ f32x4 mfma16(us8 a, us8 b, f32x4 c) {
    return __builtin_amdgcn_mfma_f32_16x16x32_bf16(
        __builtin_bit_cast(bf16x8, a), __builtin_bit_cast(bf16x8, b), c, 0, 0, 0);
}

// fp32 -> bf16 round-to-nearest-even (finite inputs)
__device__ __forceinline__ ushort_t f2bf(float f) {
    union { float f; uint32_t u; } v; v.f = f;
    uint32_t r = v.u + 0x7fffu + ((v.u >> 16) & 1u);
    return (ushort_t)(r >> 16);
}

// async global->LDS, 16B per lane. lds ptr must be wave-uniform base;
// HW writes lane i at base + i*16.
__device__ __forceinline__ void gload16(const void* g, void* l) {
    __builtin_amdgcn_global_load_lds(
        (const __attribute__((address_space(1))) void*)g,
        (__attribute__((address_space(3))) void*)l, 16, 0, 0);
}

// ---------------------------------------------------------------------------
// fp32 -> bf16 bulk convert (float4 -> us4), grid-stride
// ---------------------------------------------------------------------------
__global__ __launch_bounds__(256) void conv_f2b(const float* __restrict__ s,
                                                ushort_t* __restrict__ d, int n4)
{
    int i = blockIdx.x * blockDim.x + threadIdx.x;
    int stride = gridDim.x * blockDim.x;
    for (; i < n4; i += stride) {
        float4 v = ((const float4*)s)[i];
        us4 o;
        o[0] = f2bf(v.x); o[1] = f2bf(v.y); o[2] = f2bf(v.z); o[3] = f2bf(v.w);
        ((us4*)d)[i] = o;
    }
}

// ---------------------------------------------------------------------------
// mask tile flags at 64x64 granularity
// ---------------------------------------------------------------------------
__global__ __launch_bounds__(256) void mask_flags(const float* __restrict__ mask,
                                                  int* __restrict__ flags)
{
    int qt = blockIdx.x, kt = blockIdx.y;
    int t = threadIdx.x;
    bool nz = false;
#pragma unroll
    for (int i = 0; i < 4; i++) {
        int idx = t + i * 256;               // 1024 float4: 64 rows x 16
        int row = idx >> 4, c4 = (idx & 15) * 4;
        float4 v = *(const float4*)(mask + (size_t)(qt * 64 + row) * SEQ + kt * 64 + c4);
        nz |= (v.x != 0.f) | (v.y != 0.f) | (v.z != 0.f) | (v.w != 0.f);
    }
    if (__any((int)nz) && (t & 63) == 0) atomicOr(&flags[qt * 32 + kt], 1);
}

// ---------------------------------------------------------------------------
// bf16 GEMM  C = A @ W^T   (A: [4096][1024] bf16, W: [1024][1024] bf16 [out][in])
// m97 structure: global_load_lds 16B staging, linear LDS, BM=128 BN=64 BK=64.
// MODE 0: scatter bf16 to [B,H,S,Dh] with scale.  MODE 1: fp32 flat [4096][1024].
// ---------------------------------------------------------------------------
template<int MODE>
__global__ __launch_bounds__(256) void gemm_bt(const ushort_t* __restrict__ A,
                                               const ushort_t* __restrict__ B,
                                               void* __restrict__ Cp, float scale)
{
    __shared__ ushort_t sA[128 * 64];
    __shared__ ushort_t sB[64 * 64];
    const int t = threadIdx.x;
    const int lane = t & 63;
    const int w = t >> 6;
    const int lr = lane & 15, lg = lane >> 4;
    const int wm = (w >> 1) * 64, wn = (w & 1) * 32;
    const int m0 = blockIdx.x * 128, n0 = blockIdx.y * 64;

    f32x4 acc[4][2];
    f32x4 zero = {0.f, 0.f, 0.f, 0.f};
#pragma unroll
    for (int i = 0; i < 4; i++)
#pragma unroll
        for (int j = 0; j < 2; j++) acc[i][j] = zero;

    for (int k0 = 0; k0 < D_MODEL; k0 += 64) {
        __syncthreads();
        // ---- A tile [128][64]: 4 rounds of global_load_lds x16B ----
#pragma unroll
        for (int r = 0; r < 4; r++) {
            int chunk = r * 256 + t;                   // 1024 chunks of 8 bf16
            int row = chunk >> 3, c8 = (chunk & 7) * 8;
            gload16(A + (size_t)(m0 + row) * D_MODEL + k0 + c8,
                    &sA[(r * 256 + w * 64) * 8]);      // wave-uniform base
        }
        // ---- B tile [64][64]: 2 rounds ----
#pragma unroll
        for (int r = 0; r < 2; r++) {
            int chunk = r * 256 + t;
            int row = chunk >> 3, c8 = (chunk & 7) * 8;
            gload16(B + (size_t)(n0 + row) * D_MODEL + k0 + c8,
                    &sB[(r * 256 + w * 64) * 8]);
        }
        __syncthreads();   // drains vmcnt before s_barrier (compiler-emitted)

        us8 af[4][2], bfr[2][2];
#pragma unroll
        for (int i = 0; i < 4; i++)
#pragma unroll
            for (int ks = 0; ks < 2; ks++)
                af[i][ks] = *(const us8*)&sA[(wm + i * 16 + lr) * 64 + ks * 32 + 8 * lg];
#pragma unroll
        for (int j = 0; j < 2; j++)
#pragma unroll
            for (int ks = 0; ks < 2; ks++)
                bfr[j][ks] = *(const us8*)&sB[(wn + j * 16 + lr) * 64 + ks * 32 + 8 * lg];
#pragma unroll
        for (int i = 0; i < 4; i++)
#pragma unroll
            for (int j = 0; j < 2; j++)
#pragma unroll
                for (int ks = 0; ks < 2; ks++)
                    acc[i][j] = mfma16(af[i][ks], bfr[j][ks], acc[i][j]);
    }

    // ---- epilogue (C layout: col=lane&15, row=4*lg+r) ----
    if (MODE == 0) {
        ushort_t* C = (ushort_t*)Cp;
#pragma unroll
        for (int i = 0; i < 4; i++)
#pragma unroll
            for (int j = 0; j < 2; j++)
#pragma unroll
                for (int r = 0; r < 4; r++) {
                    int m = m0 + wm + i * 16 + 4 * lg + r;   // token row (b*S+s)
                    int n = n0 + wn + j * 16 + lr;           // feature col
                    int b = m >> 11, s = m & 2047;
                    int h = n >> 6, dh = n & 63;
                    C[(((size_t)(b * NH + h)) * SEQ + s) * DH + dh] = f2bf(acc[i][j][r] * scale);
                }
    } else {
        float* C = (float*)Cp;
#pragma unroll
        for (int i = 0; i < 4; i++)
#pragma unroll
            for (int j = 0; j < 2; j++)
#pragma unroll
                for (int r = 0; r < 4; r++) {
                    int m = m0 + wm + i * 16 + 4 * lg + r;
                    int n = n0 + wn + j * 16 + lr;
                    C[(size_t)m * D_MODEL + n] = acc[i][j][r];
                }
    }
}

// ---------------------------------------------------------------------------
// Flash attention: block = (q-tile of 64, head). 4 waves x 16 q-rows.
// Q pre-scaled by 1/sqrt(Dh). K,V: [B*H][S][Dh] bf16. Out: [B*S][D] bf16.
// XOR-swizzled LDS: byte ^= (row&7)<<4 (T2 recipe) on sK/sVT/sP.
// ---------------------------------------------------------------------------
__global__ __launch_bounds__(256) void attn_fwd(const ushort_t* __restrict__ Q,
                                                const ushort_t* __restrict__ K,
                                                const ushort_t* __restrict__ V,
                                                const float* __restrict__ mask,
                                                const int* __restrict__ flags,
                                                ushort_t* __restrict__ O)
{
    __shared__ ushort_t sK[64 * 64];
    __shared__ ushort_t sVT[64 * 64];       // rows = d, cols = kv
    __shared__ ushort_t sP[4][16 * 64];     // per-wave

    const int t = threadIdx.x, lane = t & 63, w = t >> 6;
    const int lr = lane & 15, lg = lane >> 4;
    const int qt = blockIdx.x, bh = blockIdx.y;
    const int b = bh >> 4, h = bh & 15;
    const int q0 = qt * 64 + w * 16;

    // hoist mask-tile flags into a wave bitmask (one load, no per-tile stall)
    unsigned long long fl = __ballot(lane < 32 ? (flags[qt * 32 + lane] != 0) : 0);

    // Q fragments (k-contiguous interpretation)
    us8 qf[2];
#pragma unroll
    for (int ks = 0; ks < 2; ks++)
        qf[ks] = *(const us8*)(Q + ((size_t)bh * SEQ + q0 + lr) * DH + ks * 32 + 8 * lg);

    f32x4 zero = {0.f, 0.f, 0.f, 0.f};
    f32x4 acc_o[4];
#pragma unroll
    for (int fd = 0; fd < 4; fd++) acc_o[fd] = zero;
    float m_run[4], l_run[4];
#pragma unroll
    for (int r = 0; r < 4; r++) { m_run[r] = -1e30f; l_run[r] = 0.f; }

    const ushort_t* Kb = K + (size_t)bh * SEQ * DH;
    const ushort_t* Vb = V + (size_t)bh * SEQ * DH;
    char* cK = (char*)sK;
    char* cVT = (char*)sVT;
    char* cP = (char*)sP + w * 2048;

    for (int kvt = 0; kvt < SEQ / 64; ++kvt) {
        __syncthreads();
        // ---- stage K [64][64], swizzled us4 writes ----
#pragma unroll
        for (int i = 0; i < 4; i++) {
            int idx = t + i * 256;            // 1024 chunks of 4: 64 rows x 16
            int row = idx >> 4, c = (idx & 15) * 4;
            us4 v = *(const us4*)(Kb + (size_t)(kvt * 64 + row) * DH + c);
            int by = (row * 128 + c * 2) ^ ((row & 7) << 4);
            *(us4*)(cK + by) = v;
        }
        // ---- stage V^T: wave w owns kv rows w*16..+15; lane owns column d ----
        {
            int d = lane;
            int kb = kvt * 64 + w * 16;
            us8 lo, hi;
#pragma unroll
            for (int kk = 0; kk < 8; kk++) lo[kk] = Vb[(size_t)(kb + kk) * DH + d];
#pragma unroll
            for (int kk = 0; kk < 8; kk++) hi[kk] = Vb[(size_t)(kb + 8 + kk) * DH + d];
            int b0 = (d * 128 + w * 32) ^ ((d & 7) << 4);
            int b1 = (d * 128 + w * 32 + 16) ^ ((d & 7) << 4);
            *(us8*)(cVT + b0) = lo;
            *(us8*)(cVT + b1) = hi;
        }
        __syncthreads();

        // ---- scores = Q K^T (Q pre-scaled) ----
        f32x4 sacc[4];
#pragma unroll
        for (int fn = 0; fn < 4; fn++) sacc[fn] = zero;
#pragma unroll
        for (int fn = 0; fn < 4; fn++)
#pragma unroll
            for (int ks = 0; ks < 2; ks++) {
                int row = fn * 16 + lr;
                int by = (row * 128 + (ks * 32 + 8 * lg) * 2) ^ ((row & 7) << 4);
                us8 kf = *(const us8*)(cK + by);
                sacc[fn] = mfma16(qf[ks], kf, sacc[fn]);
            }

        // ---- additive mask (skipped when tile is all-zero) ----
        if ((fl >> kvt) & 1ULL) {
#pragma unroll
            for (int r = 0; r < 4; r++) {
                int q = q0 + 4 * lg + r;
#pragma unroll
                for (int fn = 0; fn < 4; fn++)
                    sacc[fn][r] += mask[(size_t)q * SEQ + kvt * 64 + fn * 16 + lr];
            }
        }

        // ---- online softmax (rows r = 4*lg+r, 16-lane lr reduce) ----
#pragma unroll
        for (int r = 0; r < 4; r++) {
            float mx = fmaxf(fmaxf(sacc[0][r], sacc[1][r]), fmaxf(sacc[2][r], sacc[3][r]));
#pragma unroll
            for (int off = 1; off < 16; off <<= 1) mx = fmaxf(mx, __shfl_xor(mx, off));
            float mnew = fmaxf(m_run[r], mx);
            float sc = __expf(m_run[r] - mnew);
            m_run[r] = mnew;
            float rs = 0.f;
#pragma unroll
            for (int fn = 0; fn < 4; fn++) {
                float p = __expf(sacc[fn][r] - mnew);
                sacc[fn][r] = p;
                rs += p;
            }
#pragma unroll
            for (int off = 1; off < 16; off <<= 1) rs += __shfl_xor(rs, off);
            l_run[r] = l_run[r] * sc + rs;
#pragma unroll
            for (int fd = 0; fd < 4; fd++) acc_o[fd][r] *= sc;
            int qr = 4 * lg + r;
#pragma unroll
            for (int fn = 0; fn < 4; fn++) {
                int by = (qr * 128 + (fn * 16 + lr) * 2) ^ ((qr & 7) << 4);
                *(ushort_t*)(cP + by) = f2bf(sacc[fn][r]);
            }
        }

        // ---- O += P @ V ----
#pragma unroll
        for (int ks = 0; ks < 2; ks++) {
            int byp = (lr * 128 + (ks * 32 + 8 * lg) * 2) ^ ((lr & 7) << 4);
            us8 pf = *(const us8*)(cP + byp);
#pragma unroll
            for (int fd = 0; fd < 4; fd++) {
                int row = fd * 16 + lr;
                int byv = (row * 128 + (ks * 32 + 8 * lg) * 2) ^ ((row & 7) << 4);
                us8 vf = *(const us8*)(cVT + byv);
                acc_o[fd] = mfma16(pf, vf, acc_o[fd]);
            }
        }
    }

    // ---- normalize + write [B*S][D] bf16 ----
#pragma unroll
    for (int r = 0; r < 4; r++) {
        float inv = 1.f / l_run[r];
        int q = q0 + 4 * lg + r;
#pragma unroll
        for (int fd = 0; fd < 4; fd++)
            O[((size_t)(b * SEQ + q)) * D_MODEL + h * DH + fd * 16 + lr] =
                f2bf(acc_o[fd][r] * inv);
    }
}

// ---------------------------------------------------------------------------
extern "C" void kernel_launch(void* const* d_in, const int* in_sizes, int n_in,
                              void* d_out, int out_size, void* d_ws, size_t ws_size,
                              hipStream_t stream)
{
    const float* qx   = (const float*)d_in[0];
    const float* kx   = (const float*)d_in[1];
    const float* vx   = (const float*)d_in[2];
    const float* mask = (const float*)d_in[3];
    const float* wq   = (const float*)d_in[4];
    const float* wk   = (const float*)d_in[5];
    const float* wv   = (const float*)d_in[6];
    const float* w0   = (const float*)d_in[7];
    float* out = (float*)d_out;

    char* ws = (char*)d_ws;
    const size_t MB = 1024 * 1024;
    ushort_t* Abf = (ushort_t*)(ws);                // 8 MB, reused for qx/kx/vx
    ushort_t* Wq  = (ushort_t*)(ws + 8 * MB);       // 2 MB each
    ushort_t* Wk  = (ushort_t*)(ws + 10 * MB);
    ushort_t* Wv  = (ushort_t*)(ws + 12 * MB);
    ushort_t* W0  = (ushort_t*)(ws + 14 * MB);
    ushort_t* Vv  = (ushort_t*)(ws + 16 * MB);      // [B,H,S,Dh] bf16, 8 MB
    ushort_t* AO  = (ushort_t*)(ws + 24 * MB);      // [B*S][D] bf16, 8 MB
    int* flags    = (int*)(ws + 32 * MB);           // [32][32]
    // Q and K live in d_out (16 MB fp32) until attn consumes them
    ushort_t* Qb = (ushort_t*)d_out;
    ushort_t* Kb = (ushort_t*)d_out + 4 * MB;       // halfword offset = 8 MB bytes

    hipMemsetAsync(flags, 0, 32 * 32 * sizeof(int), stream);
    mask_flags<<<dim3(32, 32), 256, 0, stream>>>(mask, flags);

    // weights fp32 -> bf16
    conv_f2b<<<1024, 256, 0, stream>>>(wq, Wq, 262144);
    conv_f2b<<<1024, 256, 0, stream>>>(wk, Wk, 262144);
    conv_f2b<<<1024, 256, 0, stream>>>(wv, Wv, 262144);
    conv_f2b<<<1024, 256, 0, stream>>>(w0, W0, 262144);

    dim3 g(MROWS / 128, D_MODEL / 64);              // (32, 16) = 512 blocks
    conv_f2b<<<2048, 256, 0, stream>>>(qx, Abf, 1048576);
    gemm_bt<0><<<g, 256, 0, stream>>>(Abf, Wq, Qb, 0.125f);   // fold 1/sqrt(64)
    conv_f2b<<<2048, 256, 0, stream>>>(kx, Abf, 1048576);
    gemm_bt<0><<<g, 256, 0, stream>>>(Abf, Wk, Kb, 1.0f);
    conv_f2b<<<2048, 256, 0, stream>>>(vx, Abf, 1048576);
    gemm_bt<0><<<g, 256, 0, stream>>>(Abf, Wv, Vv, 1.0f);

    attn_fwd<<<dim3(32, 32), 256, 0, stream>>>(Qb, Kb, Vv, mask, flags, AO);

    gemm_bt<1><<<g, 256, 0, stream>>>(AO, W0, out, 1.0f);
}